// Round 1
// baseline (1676.873 us; speedup 1.0000x reference)
//
#include <hip/hip_runtime.h>
#include <math.h>

#define BQ 4
#define DM 192
#define DI 384
#define HH 48
#define WW 48
#define LL 2304
#define KK 4
#define NN 16
#define RR 12

__device__ __forceinline__ float gelu_exact(float x) {
    return 0.5f * x * (1.0f + erff(x * 0.7071067811865476f));
}

__device__ __forceinline__ float softplus_f(float x) {
    return fmaxf(x, 0.0f) + log1pf(expf(-fabsf(x)));
}

// Position in row-major xc space corresponding to scan-index l of direction k.
// Same formula serves both the gather (u read) and the cross-merge scatter.
__device__ __forceinline__ int pos_for(int k, int l) {
    if (k == 0) return l;
    if (k == 1) { return (l % HH) * WW + (l / HH); }
    if (k == 2) return (LL - 1) - l;
    int j = (LL - 1) - l;
    return (j % HH) * WW + (j / HH);
}

// ---------------- K1: in_proj 1x1 (768x192 GEMM), split -> xc_pre, gelu(z)->z1
__global__ __launch_bounds__(256) void k_inproj(const float* __restrict__ x,
                                                const float* __restrict__ w,
                                                float* __restrict__ xc_pre,
                                                float* __restrict__ z1) {
    __shared__ float xt[16 * 193];  // [lt][d], stride 193 to dodge bank conflicts
    const int nt = LL / 16;  // 144
    int b = blockIdx.x / nt;
    int l0 = (blockIdx.x % nt) * 16;
    int tid = threadIdx.x;
    for (int idx = tid; idx < DM * 16; idx += 256) {
        int lt = idx & 15, d = idx >> 4;
        xt[lt * 193 + d] = x[(size_t)(b * DM + d) * LL + l0 + lt];
    }
    __syncthreads();
    for (int pass = 0; pass < 12; ++pass) {
        int t = pass * 256 + tid;      // 768 o * 4 ltq = 3072 tasks
        int o = t >> 2, ltq = t & 3;
        float s0 = 0.f, s1 = 0.f, s2 = 0.f, s3 = 0.f;
        const float* wr = w + (size_t)o * DM;
        int base = (ltq * 4) * 193;
        for (int d = 0; d < DM; ++d) {
            float wv = wr[d];
            s0 += wv * xt[base + d];
            s1 += wv * xt[base + 193 + d];
            s2 += wv * xt[base + 2 * 193 + d];
            s3 += wv * xt[base + 3 * 193 + d];
        }
        int l = l0 + ltq * 4;
        if (o < DI) {
            float* p = xc_pre + (size_t)(b * DI + o) * LL + l;
            p[0] = s0; p[1] = s1; p[2] = s2; p[3] = s3;
        } else {
            int oz = o - DI;
            float* p = z1 + (size_t)(b * LL + l) * DI + oz;
            p[0]        = gelu_exact(s0);
            p[DI]       = gelu_exact(s1);
            p[2 * DI]   = gelu_exact(s2);
            p[3 * DI]   = gelu_exact(s3);
        }
    }
}

// ---------------- K2: depthwise 3x3 conv + bias + gelu
__global__ __launch_bounds__(256) void k_dwconv(const float* __restrict__ xc_pre,
                                                const float* __restrict__ cw,
                                                const float* __restrict__ cb,
                                                float* __restrict__ xc_conv) {
    int idx = blockIdx.x * 256 + threadIdx.x;
    if (idx >= BQ * DI * LL) return;
    int l = idx % LL;
    int tmp = idx / LL;
    int c = tmp % DI;
    int b = tmp / DI;
    int h = l / WW, w = l % WW;
    const float* in = xc_pre + (size_t)(b * DI + c) * LL;
    const float* k9 = cw + c * 9;
    float s = cb[c];
    #pragma unroll
    for (int dh = -1; dh <= 1; ++dh) {
        int hh = h + dh;
        if (hh < 0 || hh >= HH) continue;
        #pragma unroll
        for (int dw = -1; dw <= 1; ++dw) {
            int ww = w + dw;
            if (ww < 0 || ww >= WW) continue;
            s += in[hh * WW + ww] * k9[(dh + 1) * 3 + (dw + 1)];
        }
    }
    xc_conv[idx] = gelu_exact(s);
}

// ---------------- K3: x_proj per direction -> dts (B,K,L,R), Bs/Cs (B,K,L,N)
__global__ __launch_bounds__(256) void k_xproj(const float* __restrict__ xc_conv,
                                               const float* __restrict__ xpw,
                                               float* __restrict__ dts,
                                               float* __restrict__ Bsb,
                                               float* __restrict__ Csb) {
    __shared__ float xt[16 * 385];  // [lt][d]
    const int nt = LL / 16;
    int l0 = (blockIdx.x % nt) * 16;
    int bk = blockIdx.x / nt;      // b*KK + k
    int k = bk % KK;
    int b = bk / KK;
    for (int idx = threadIdx.x; idx < DI * 16; idx += 256) {
        int lt = idx & 15, d = idx >> 4;
        int pos = pos_for(k, l0 + lt);
        xt[lt * 385 + d] = xc_conv[(size_t)(b * DI + d) * LL + pos];
    }
    __syncthreads();
    int t = threadIdx.x;
    if (t < 176) {                 // 44 c * 4 ltq
        int c = t >> 2, ltq = t & 3;
        float s0 = 0.f, s1 = 0.f, s2 = 0.f, s3 = 0.f;
        const float* wr = xpw + (size_t)(k * 44 + c) * DI;
        int base = (ltq * 4) * 385;
        for (int d = 0; d < DI; ++d) {
            float wv = wr[d];
            s0 += wv * xt[base + d];
            s1 += wv * xt[base + 385 + d];
            s2 += wv * xt[base + 2 * 385 + d];
            s3 += wv * xt[base + 3 * 385 + d];
        }
        float sv[4] = {s0, s1, s2, s3};
        #pragma unroll
        for (int j = 0; j < 4; ++j) {
            int l = l0 + ltq * 4 + j;
            if (c < RR)
                dts[((size_t)bk * LL + l) * RR + c] = sv[j];
            else if (c < RR + NN)
                Bsb[((size_t)bk * LL + l) * NN + (c - RR)] = sv[j];
            else
                Csb[((size_t)bk * LL + l) * NN + (c - RR - NN)] = sv[j];
        }
    }
}

// ---------------- K4: selective scan. 16 lanes per (b,k,d), one n per lane.
// delta/u computed in 16-step batches (one step per lane) and shfl-broadcast.
// Cross-merge fused: atomicAdd into ym (B,L,DI); 4 adds per target (one per k).
__global__ __launch_bounds__(256) void k_scan(const float* __restrict__ xc_conv,
                                              const float* __restrict__ dts,
                                              const float* __restrict__ Bsb,
                                              const float* __restrict__ Csb,
                                              const float* __restrict__ dtw_g,
                                              const float* __restrict__ dtb_g,
                                              const float* __restrict__ Alogs,
                                              const float* __restrict__ Ds_g,
                                              float* __restrict__ ym) {
    int blk = blockIdx.x;           // (b*KK + k)*24 + dchunk
    int dchunk = blk % 24;
    int bk = blk / 24;
    int k = bk % KK;
    int b = bk / KK;
    int tid = threadIdx.x;
    int lane = tid & 63;
    int wv = tid >> 6;
    int n = lane & 15;
    int sub = lane >> 4;
    int d = dchunk * 16 + wv * 4 + sub;
    int kd = k * DI + d;

    float A = -expf(Alogs[(size_t)kd * NN + n]);
    float Dv = Ds_g[kd];
    float dtb = dtb_g[kd];
    float dtw[RR];
    #pragma unroll
    for (int r = 0; r < RR; ++r) dtw[r] = dtw_g[(size_t)kd * RR + r];

    const float* dts_p = dts + (size_t)bk * LL * RR;
    const float* Bp = Bsb + (size_t)bk * LL * NN;
    const float* Cp = Csb + (size_t)bk * LL * NN;
    const float* up = xc_conv + (size_t)(b * DI + d) * LL;
    float* ymp = ym + (size_t)b * LL * DI;

    float h = 0.f;
    float delta_blk = 0.f, u_blk = 0.f;
    int srcbase = lane & ~15;

    for (int l = 0; l < LL; ++l) {
        int j = l & 15;
        if (j == 0) {
            int lme = l + n;        // this lane precomputes step l+n
            const float* dp = dts_p + (size_t)lme * RR;
            float acc = dtb;
            #pragma unroll
            for (int r = 0; r < RR; ++r) acc += dp[r] * dtw[r];
            delta_blk = softplus_f(acc);
            u_blk = up[pos_for(k, lme)];
        }
        float delta = __shfl(delta_blk, srcbase + j, 64);
        float u = __shfl(u_blk, srcbase + j, 64);
        float Bv = Bp[(size_t)l * NN + n];
        float Cv = Cp[(size_t)l * NN + n];
        h = h * __expf(delta * A) + (delta * u) * Bv;
        float yp = h * Cv;
        yp += __shfl_xor(yp, 8, 64);
        yp += __shfl_xor(yp, 4, 64);
        yp += __shfl_xor(yp, 2, 64);
        yp += __shfl_xor(yp, 1, 64);
        if (n == 0) {
            int t = pos_for(k, l);
            atomicAdd(&ymp[(size_t)t * DI + d], yp + u * Dv);
        }
    }
}

// ---------------- K5: LayerNorm over channel + gate with gelu(z)
__global__ __launch_bounds__(384) void k_ln_gate(const float* __restrict__ ym,
                                                 const float* __restrict__ z1,
                                                 const float* __restrict__ lnw,
                                                 const float* __restrict__ lnb,
                                                 float* __restrict__ gbuf) {
    int pos = blockIdx.x;           // b*LL + l
    int d = threadIdx.x;
    float v = ym[(size_t)pos * DI + d];
    float s = v, q = v * v;
    #pragma unroll
    for (int o = 32; o >= 1; o >>= 1) {
        s += __shfl_xor(s, o, 64);
        q += __shfl_xor(q, o, 64);
    }
    __shared__ float ssum[6], sqq[6];
    int lane = d & 63, w = d >> 6;
    if (lane == 0) { ssum[w] = s; sqq[w] = q; }
    __syncthreads();
    float ts = 0.f, tq = 0.f;
    #pragma unroll
    for (int i = 0; i < 6; ++i) { ts += ssum[i]; tq += sqq[i]; }
    float mu = ts / (float)DI;
    float var = tq / (float)DI - mu * mu;
    float inv = rsqrtf(var + 1e-5f);
    float y = (v - mu) * inv * lnw[d] + lnb[d];
    gbuf[(size_t)pos * DI + d] = y * z1[(size_t)pos * DI + d];
}

// ---------------- K6: out_proj 1x1 (192x384 GEMM)
__global__ __launch_bounds__(256) void k_outproj(const float* __restrict__ gbuf,
                                                 const float* __restrict__ w,
                                                 float* __restrict__ out) {
    __shared__ float xt[16 * 385];  // [lt][d]
    const int nt = LL / 16;
    int b = blockIdx.x / nt;
    int l0 = (blockIdx.x % nt) * 16;
    for (int idx = threadIdx.x; idx < DI * 16; idx += 256) {
        int d = idx % DI;
        int lt = idx / DI;
        xt[lt * 385 + d] = gbuf[(size_t)(b * LL + l0 + lt) * DI + d];
    }
    __syncthreads();
    for (int pass = 0; pass < 3; ++pass) {
        int t = pass * 256 + threadIdx.x;  // 192 o * 4 ltq = 768 tasks
        int o = t >> 2, ltq = t & 3;
        float s0 = 0.f, s1 = 0.f, s2 = 0.f, s3 = 0.f;
        const float* wr = w + (size_t)o * DI;
        int base = (ltq * 4) * 385;
        for (int d = 0; d < DI; ++d) {
            float wv = wr[d];
            s0 += wv * xt[base + d];
            s1 += wv * xt[base + 385 + d];
            s2 += wv * xt[base + 2 * 385 + d];
            s3 += wv * xt[base + 3 * 385 + d];
        }
        float* p = out + (size_t)(b * DM + o) * LL + l0 + ltq * 4;
        p[0] = s0; p[1] = s1; p[2] = s2; p[3] = s3;
    }
}

extern "C" void kernel_launch(void* const* d_in, const int* in_sizes, int n_in,
                              void* d_out, int out_size, void* d_ws, size_t ws_size,
                              hipStream_t stream) {
    (void)in_sizes; (void)n_in; (void)out_size; (void)ws_size;
    const float* x      = (const float*)d_in[0];
    const float* ipw    = (const float*)d_in[1];
    const float* cw     = (const float*)d_in[2];
    const float* cb     = (const float*)d_in[3];
    const float* xpw    = (const float*)d_in[4];
    const float* dtw    = (const float*)d_in[5];
    const float* dtb    = (const float*)d_in[6];
    const float* Alogs  = (const float*)d_in[7];
    const float* Ds     = (const float*)d_in[8];
    const float* lnw    = (const float*)d_in[9];
    const float* lnb    = (const float*)d_in[10];
    const float* opw    = (const float*)d_in[11];
    float* out = (float*)d_out;

    float* wsf = (float*)d_ws;
    const size_t SZ = (size_t)BQ * DI * LL;        // 3,538,944
    float* z1      = wsf;                          // (B,L,DI)
    float* xc_pre  = wsf + SZ;                     // (B,DI,L); reused as gbuf
    float* xc_conv = wsf + 2 * SZ;                 // (B,DI,L)
    float* dts     = wsf + 3 * SZ;                 // (B,K,L,R)
    float* Bsb     = dts + (size_t)BQ * KK * LL * RR;   // (B,K,L,N)
    float* Csb     = Bsb + (size_t)BQ * KK * LL * NN;   // (B,K,L,N)
    float* ym      = Csb + (size_t)BQ * KK * LL * NN;   // (B,L,DI)

    hipMemsetAsync(ym, 0, SZ * sizeof(float), stream);

    k_inproj<<<BQ * (LL / 16), 256, 0, stream>>>(x, ipw, xc_pre, z1);
    k_dwconv<<<(BQ * DI * LL) / 256, 256, 0, stream>>>(xc_pre, cw, cb, xc_conv);
    k_xproj<<<BQ * KK * (LL / 16), 256, 0, stream>>>(xc_conv, xpw, dts, Bsb, Csb);
    k_scan<<<BQ * KK * 24, 256, 0, stream>>>(xc_conv, dts, Bsb, Csb, dtw, dtb,
                                             Alogs, Ds, ym);
    k_ln_gate<<<BQ * LL, 384, 0, stream>>>(ym, z1, lnw, lnb, xc_pre);
    k_outproj<<<BQ * (LL / 16), 256, 0, stream>>>(xc_pre, opw, out);
}

// Round 2
// 650.825 us; speedup vs baseline: 2.5765x; 2.5765x over previous
//
#include <hip/hip_runtime.h>
#include <math.h>

#define BQ 4
#define DM 192
#define DI 384
#define HH 48
#define WW 48
#define LL 2304
#define KK 4
#define NN 16
#define RR 12
#define CH 24      // chunks per sequence (CLEN divisible by 16, 48 | CLEN)
#define CLEN 96
#define NBATCH 6   // CLEN/16

__device__ __forceinline__ float gelu_exact(float x) {
    return 0.5f * x * (1.0f + erff(x * 0.7071067811865476f));
}

__device__ __forceinline__ float softplus_f(float x) {
    return fmaxf(x, 0.0f) + log1pf(expf(-fabsf(x)));
}

__device__ __forceinline__ int pos_for(int k, int l) {
    if (k == 0) return l;
    if (k == 1) { return (l % HH) * WW + (l / HH); }
    if (k == 2) return (LL - 1) - l;
    int j = (LL - 1) - l;
    return (j % HH) * WW + (j / HH);
}

// DPP move: ctrl 0x00-0xFF = quad_perm, 0xB1 = xor1, 0x4E = xor2.
template<int CTRL>
__device__ __forceinline__ float dpp_movf(float v) {
    return __int_as_float(__builtin_amdgcn_update_dpp(
        0, __float_as_int(v), CTRL, 0xF, 0xF, true));
}

// ---------------- K1: in_proj 1x1 (768x192 GEMM), split -> xc_pre, gelu(z)->z1
__global__ __launch_bounds__(256) void k_inproj(const float* __restrict__ x,
                                                const float* __restrict__ w,
                                                float* __restrict__ xc_pre,
                                                float* __restrict__ z1) {
    __shared__ float xt[16 * 193];
    const int nt = LL / 16;
    int b = blockIdx.x / nt;
    int l0 = (blockIdx.x % nt) * 16;
    int tid = threadIdx.x;
    for (int idx = tid; idx < DM * 16; idx += 256) {
        int lt = idx & 15, d = idx >> 4;
        xt[lt * 193 + d] = x[(size_t)(b * DM + d) * LL + l0 + lt];
    }
    __syncthreads();
    for (int pass = 0; pass < 12; ++pass) {
        int t = pass * 256 + tid;
        int o = t >> 2, ltq = t & 3;
        float s0 = 0.f, s1 = 0.f, s2 = 0.f, s3 = 0.f;
        const float* wr = w + (size_t)o * DM;
        int base = (ltq * 4) * 193;
        for (int d = 0; d < DM; ++d) {
            float wv = wr[d];
            s0 += wv * xt[base + d];
            s1 += wv * xt[base + 193 + d];
            s2 += wv * xt[base + 2 * 193 + d];
            s3 += wv * xt[base + 3 * 193 + d];
        }
        int l = l0 + ltq * 4;
        if (o < DI) {
            float* p = xc_pre + (size_t)(b * DI + o) * LL + l;
            p[0] = s0; p[1] = s1; p[2] = s2; p[3] = s3;
        } else {
            int oz = o - DI;
            float* p = z1 + (size_t)(b * LL + l) * DI + oz;
            p[0]        = gelu_exact(s0);
            p[DI]       = gelu_exact(s1);
            p[2 * DI]   = gelu_exact(s2);
            p[3 * DI]   = gelu_exact(s3);
        }
    }
}

// ---------------- K2: depthwise 3x3 conv + bias + gelu
__global__ __launch_bounds__(256) void k_dwconv(const float* __restrict__ xc_pre,
                                                const float* __restrict__ cw,
                                                const float* __restrict__ cb,
                                                float* __restrict__ xc_conv) {
    int idx = blockIdx.x * 256 + threadIdx.x;
    if (idx >= BQ * DI * LL) return;
    int l = idx % LL;
    int tmp = idx / LL;
    int c = tmp % DI;
    int b = tmp / DI;
    int h = l / WW, w = l % WW;
    const float* in = xc_pre + (size_t)(b * DI + c) * LL;
    const float* k9 = cw + c * 9;
    float s = cb[c];
    #pragma unroll
    for (int dh = -1; dh <= 1; ++dh) {
        int hh = h + dh;
        if (hh < 0 || hh >= HH) continue;
        #pragma unroll
        for (int dw = -1; dw <= 1; ++dw) {
            int ww = w + dw;
            if (ww < 0 || ww >= WW) continue;
            s += in[hh * WW + ww] * k9[(dh + 1) * 3 + (dw + 1)];
        }
    }
    xc_conv[idx] = gelu_exact(s);
}

// ---------------- K3: x_proj per direction -> dts (B,K,L,R), Bs/Cs (B,K,L,N)
__global__ __launch_bounds__(256) void k_xproj(const float* __restrict__ xc_conv,
                                               const float* __restrict__ xpw,
                                               float* __restrict__ dts,
                                               float* __restrict__ Bsb,
                                               float* __restrict__ Csb) {
    __shared__ float xt[16 * 385];
    const int nt = LL / 16;
    int l0 = (blockIdx.x % nt) * 16;
    int bk = blockIdx.x / nt;
    int k = bk % KK;
    int b = bk / KK;
    for (int idx = threadIdx.x; idx < DI * 16; idx += 256) {
        int lt = idx & 15, d = idx >> 4;
        int pos = pos_for(k, l0 + lt);
        xt[lt * 385 + d] = xc_conv[(size_t)(b * DI + d) * LL + pos];
    }
    __syncthreads();
    int t = threadIdx.x;
    if (t < 176) {
        int c = t >> 2, ltq = t & 3;
        float s0 = 0.f, s1 = 0.f, s2 = 0.f, s3 = 0.f;
        const float* wr = xpw + (size_t)(k * 44 + c) * DI;
        int base = (ltq * 4) * 385;
        for (int d = 0; d < DI; ++d) {
            float wv = wr[d];
            s0 += wv * xt[base + d];
            s1 += wv * xt[base + 385 + d];
            s2 += wv * xt[base + 2 * 385 + d];
            s3 += wv * xt[base + 3 * 385 + d];
        }
        float sv[4] = {s0, s1, s2, s3};
        #pragma unroll
        for (int j = 0; j < 4; ++j) {
            int l = l0 + ltq * 4 + j;
            if (c < RR)
                dts[((size_t)bk * LL + l) * RR + c] = sv[j];
            else if (c < RR + NN)
                Bsb[((size_t)bk * LL + l) * NN + (c - RR)] = sv[j];
            else
                Csb[((size_t)bk * LL + l) * NN + (c - RR - NN)] = sv[j];
        }
    }
}

// ---------------- Chunked selective scan.
// Lane layout: quad lane q owns n in [4q,4q+4); 16 d's per wave; 64 d's per block.
// Batch: every 16 steps, quad lane q computes delta/u for steps q*4+i; per-step
// broadcast via DPP quad_perm (pure VALU, no LDS).
// P1 (P3=false): h from 0, store end-state hst and chunk sum-of-delta td_st.
// P3 (P3=true): h from hin_st, produce y, fused cross-merge via atomicAdd.
template<bool P3>
__global__ __launch_bounds__(256) void k_scan_chunk(
    const float* __restrict__ xc_conv,
    const float* __restrict__ dts,
    const float* __restrict__ Bsb,
    const float* __restrict__ Csb,
    const float* __restrict__ dtw_g,
    const float* __restrict__ dtb_g,
    const float* __restrict__ Alogs,
    const float* __restrict__ Ds_g,
    const float* __restrict__ hin_st,
    float* __restrict__ hst,
    float* __restrict__ td_st,
    float* __restrict__ ym)
{
    int blk = blockIdx.x;                 // ((bk*CH + c)*6 + dblk)
    int dblk = blk % 6;
    int tmp = blk / 6;
    int c = tmp % CH;
    int bk = tmp / CH;
    int k = bk & 3, b = bk >> 2;
    int tid = threadIdx.x;
    int lane = tid & 63, wv = tid >> 6;
    int q = lane & 3;
    int d16 = lane >> 2;
    int d = dblk * 64 + wv * 16 + d16;
    int kd = k * DI + d;
    int n0 = q << 2;

    float4 Al = *(const float4*)(Alogs + (size_t)kd * NN + n0);
    float A[4] = { -expf(Al.x), -expf(Al.y), -expf(Al.z), -expf(Al.w) };
    float dtb = dtb_g[kd];
    float dtw[12];
    {
        const float4* p = (const float4*)(dtw_g + (size_t)kd * RR);
        float4 a0 = p[0], a1 = p[1], a2 = p[2];
        dtw[0]=a0.x; dtw[1]=a0.y; dtw[2]=a0.z;  dtw[3]=a0.w;
        dtw[4]=a1.x; dtw[5]=a1.y; dtw[6]=a1.z;  dtw[7]=a1.w;
        dtw[8]=a2.x; dtw[9]=a2.y; dtw[10]=a2.z; dtw[11]=a2.w;
    }
    const float* up  = xc_conv + (size_t)(b * DI + d) * LL;
    const float* dtp = dts + (size_t)bk * LL * RR;
    const float* Bp  = Bsb + (size_t)bk * LL * NN;
    const float* Cp  = Csb + (size_t)bk * LL * NN;

    int l0 = c * CLEN;
    float h[4];
    if (P3) {
        float4 h4 = *(const float4*)(hin_st + ((size_t)(bk * CH + c) * DI + d) * NN + n0);
        h[0] = h4.x; h[1] = h4.y; h[2] = h4.z; h[3] = h4.w;
    } else {
        h[0] = h[1] = h[2] = h[3] = 0.f;
    }
    float Dv = P3 ? Ds_g[kd] : 0.f;
    float* ymp = ym + (size_t)b * LL * DI;
    int pos = 0, cnt = 0;
    if (P3) { pos = pos_for(k, l0); cnt = 0; }   // l0 % 48 == 0 always
    float td = 0.f;

    for (int g = 0; g < NBATCH; ++g) {
        int lb = l0 + g * 16;
        float deltab[4], ub[4];
        #pragma unroll
        for (int i = 0; i < 4; ++i) {
            int lme = lb + n0 + i;
            const float4* dp4 = (const float4*)(dtp + (size_t)lme * RR);
            float4 x0 = dp4[0], x1 = dp4[1], x2 = dp4[2];
            float acc = dtb
                + x0.x*dtw[0] + x0.y*dtw[1] + x0.z*dtw[2]  + x0.w*dtw[3]
                + x1.x*dtw[4] + x1.y*dtw[5] + x1.z*dtw[6]  + x1.w*dtw[7]
                + x2.x*dtw[8] + x2.y*dtw[9] + x2.z*dtw[10] + x2.w*dtw[11];
            float del = softplus_f(acc);
            deltab[i] = del;
            ub[i] = up[pos_for(k, lme)];
            if (!P3) { td += del; deltab[i] = del; ub[i] *= del; } // pass1: ub holds du
        }

#define SSTEP(J) { \
        constexpr int S_ = (J) >> 2, I_ = (J) & 3; \
        float delta = dpp_movf<S_ * 0x55>(deltab[I_]); \
        float ub_b  = dpp_movf<S_ * 0x55>(ub[I_]); \
        float du = P3 ? (delta * ub_b) : ub_b; \
        float4 B4 = *(const float4*)(Bp + (size_t)(lb + (J)) * NN + n0); \
        float dA0 = __expf(delta * A[0]); h[0] = h[0] * dA0 + du * B4.x; \
        float dA1 = __expf(delta * A[1]); h[1] = h[1] * dA1 + du * B4.y; \
        float dA2 = __expf(delta * A[2]); h[2] = h[2] * dA2 + du * B4.z; \
        float dA3 = __expf(delta * A[3]); h[3] = h[3] * dA3 + du * B4.w; \
        if (P3) { \
            float4 C4 = *(const float4*)(Cp + (size_t)(lb + (J)) * NN + n0); \
            float yp = h[0]*C4.x + h[1]*C4.y + h[2]*C4.z + h[3]*C4.w; \
            yp += dpp_movf<0xB1>(yp); \
            yp += dpp_movf<0x4E>(yp); \
            if (q == 0) atomicAdd(&ymp[(size_t)pos * DI + d], yp + ub_b * Dv); \
            if (k == 0) pos += 1; \
            else if (k == 2) pos -= 1; \
            else { \
                bool wr_ = (cnt == 47); \
                if (k == 1) pos += wr_ ? -2255 : 48; \
                else        pos += wr_ ? 2255 : -48; \
                cnt = wr_ ? 0 : cnt + 1; \
            } \
        } }

        SSTEP(0)  SSTEP(1)  SSTEP(2)  SSTEP(3)
        SSTEP(4)  SSTEP(5)  SSTEP(6)  SSTEP(7)
        SSTEP(8)  SSTEP(9)  SSTEP(10) SSTEP(11)
        SSTEP(12) SSTEP(13) SSTEP(14) SSTEP(15)
#undef SSTEP
    }

    if (!P3) {
        td += dpp_movf<0xB1>(td);
        td += dpp_movf<0x4E>(td);
        size_t base = ((size_t)(bk * CH + c) * DI + d) * NN + n0;
        float4 h4; h4.x = h[0]; h4.y = h[1]; h4.z = h[2]; h4.w = h[3];
        *(float4*)(hst + base) = h4;
        if (q == 0) td_st[(size_t)(bk * CH + c) * DI + d] = td;
    }
}

// ---------------- combine: sequential over CH chunks per (bk,d,n)
__global__ __launch_bounds__(256) void k_scan_combine(
    const float* __restrict__ hst,
    const float* __restrict__ td_st,
    const float* __restrict__ Alogs,
    float* __restrict__ hin_st)
{
    int t = blockIdx.x * 256 + threadIdx.x;   // B*K*DI*NN = 98304
    int n = t & 15;
    int d = (t >> 4) % DI;
    int bk = t / (DI * NN);
    int k = bk & 3;
    float A = -expf(Alogs[(size_t)(k * DI + d) * NN + n]);
    float h = 0.f;
    for (int c = 0; c < CH; ++c) {
        size_t rb = (size_t)(bk * CH + c) * DI + d;
        hin_st[rb * NN + n] = h;
        float P = __expf(A * td_st[rb]);
        h = P * h + hst[rb * NN + n];
    }
}

// ---------------- K5: LayerNorm over channel + gate with gelu(z)
__global__ __launch_bounds__(384) void k_ln_gate(const float* __restrict__ ym,
                                                 const float* __restrict__ z1,
                                                 const float* __restrict__ lnw,
                                                 const float* __restrict__ lnb,
                                                 float* __restrict__ gbuf) {
    int pos = blockIdx.x;
    int d = threadIdx.x;
    float v = ym[(size_t)pos * DI + d];
    float s = v, qq = v * v;
    #pragma unroll
    for (int o = 32; o >= 1; o >>= 1) {
        s += __shfl_xor(s, o, 64);
        qq += __shfl_xor(qq, o, 64);
    }
    __shared__ float ssum[6], sqq[6];
    int lane = d & 63, w = d >> 6;
    if (lane == 0) { ssum[w] = s; sqq[w] = qq; }
    __syncthreads();
    float ts = 0.f, tq = 0.f;
    #pragma unroll
    for (int i = 0; i < 6; ++i) { ts += ssum[i]; tq += sqq[i]; }
    float mu = ts / (float)DI;
    float var = tq / (float)DI - mu * mu;
    float inv = rsqrtf(var + 1e-5f);
    float y = (v - mu) * inv * lnw[d] + lnb[d];
    gbuf[(size_t)pos * DI + d] = y * z1[(size_t)pos * DI + d];
}

// ---------------- K6: out_proj 1x1 (192x384 GEMM)
__global__ __launch_bounds__(256) void k_outproj(const float* __restrict__ gbuf,
                                                 const float* __restrict__ w,
                                                 float* __restrict__ out) {
    __shared__ float xt[16 * 385];
    const int nt = LL / 16;
    int b = blockIdx.x / nt;
    int l0 = (blockIdx.x % nt) * 16;
    for (int idx = threadIdx.x; idx < DI * 16; idx += 256) {
        int d = idx % DI;
        int lt = idx / DI;
        xt[lt * 385 + d] = gbuf[(size_t)(b * LL + l0 + lt) * DI + d];
    }
    __syncthreads();
    for (int pass = 0; pass < 3; ++pass) {
        int t = pass * 256 + threadIdx.x;
        int o = t >> 2, ltq = t & 3;
        float s0 = 0.f, s1 = 0.f, s2 = 0.f, s3 = 0.f;
        const float* wr = w + (size_t)o * DI;
        int base = (ltq * 4) * 385;
        for (int d = 0; d < DI; ++d) {
            float wv = wr[d];
            s0 += wv * xt[base + d];
            s1 += wv * xt[base + 385 + d];
            s2 += wv * xt[base + 2 * 385 + d];
            s3 += wv * xt[base + 3 * 385 + d];
        }
        float* p = out + (size_t)(b * DM + o) * LL + l0 + ltq * 4;
        p[0] = s0; p[1] = s1; p[2] = s2; p[3] = s3;
    }
}

extern "C" void kernel_launch(void* const* d_in, const int* in_sizes, int n_in,
                              void* d_out, int out_size, void* d_ws, size_t ws_size,
                              hipStream_t stream) {
    (void)in_sizes; (void)n_in; (void)out_size; (void)ws_size;
    const float* x      = (const float*)d_in[0];
    const float* ipw    = (const float*)d_in[1];
    const float* cw     = (const float*)d_in[2];
    const float* cb     = (const float*)d_in[3];
    const float* xpw    = (const float*)d_in[4];
    const float* dtw    = (const float*)d_in[5];
    const float* dtb    = (const float*)d_in[6];
    const float* Alogs  = (const float*)d_in[7];
    const float* Ds     = (const float*)d_in[8];
    const float* lnw    = (const float*)d_in[9];
    const float* lnb    = (const float*)d_in[10];
    const float* opw    = (const float*)d_in[11];
    float* out = (float*)d_out;

    float* wsf = (float*)d_ws;
    const size_t SZ = (size_t)BQ * DI * LL;            // 3,538,944 floats
    float* z1      = wsf;                              // (B,L,DI)
    float* xc_pre  = wsf + SZ;                         // (B,DI,L); later hin_st, then gbuf
    float* xc_conv = wsf + 2 * SZ;                     // (B,DI,L)
    float* dts     = wsf + 3 * SZ;                     // (B,K,L,R)
    float* Bsb     = dts + (size_t)BQ * KK * LL * RR;  // (B,K,L,N)
    float* Csb     = Bsb + (size_t)BQ * KK * LL * NN;  // (B,K,L,N)
    float* ym      = Csb + (size_t)BQ * KK * LL * NN;  // (B,L,DI); pass1 scratch first

    const size_t CST = (size_t)BQ * KK * CH * DI * NN; // 2,359,296 floats
    float* hst    = ym;                                // pass1 end-states (in ym region)
    float* td_st  = ym + CST;                          // chunk delta-sums (fits: CST+147K < SZ)
    float* hin_st = xc_pre;                            // chunk incoming states (in xc_pre)

    k_inproj<<<BQ * (LL / 16), 256, 0, stream>>>(x, ipw, xc_pre, z1);
    k_dwconv<<<(BQ * DI * LL) / 256, 256, 0, stream>>>(xc_pre, cw, cb, xc_conv);
    k_xproj<<<BQ * KK * (LL / 16), 256, 0, stream>>>(xc_conv, xpw, dts, Bsb, Csb);

    const int scan_grid = BQ * KK * CH * 6;            // 2304 blocks
    k_scan_chunk<false><<<scan_grid, 256, 0, stream>>>(
        xc_conv, dts, Bsb, Csb, dtw, dtb, Alogs, Ds, nullptr, hst, td_st, ym);
    k_scan_combine<<<(BQ * KK * DI * NN) / 256, 256, 0, stream>>>(
        hst, td_st, Alogs, hin_st);
    hipMemsetAsync(ym, 0, SZ * sizeof(float), stream);
    k_scan_chunk<true><<<scan_grid, 256, 0, stream>>>(
        xc_conv, dts, Bsb, Csb, dtw, dtb, Alogs, Ds, hin_st, nullptr, nullptr, ym);

    k_ln_gate<<<BQ * LL, 384, 0, stream>>>(ym, z1, lnw, lnb, xc_pre);
    k_outproj<<<BQ * (LL / 16), 256, 0, stream>>>(xc_pre, opw, out);
}